// Round 14
// baseline (325.840 us; speedup 1.0000x reference)
//
#include <hip/hip_runtime.h>

typedef __attribute__((ext_vector_type(8))) short short8;
typedef __attribute__((ext_vector_type(4))) float f32x4;
typedef __attribute__((ext_vector_type(4))) unsigned int u32x4;
typedef unsigned short u16;
typedef unsigned int u32;

#define XH 114
#define XW 114
#define CINC 64
#define COUT 128
#define OH 112
#define OW 112
#define NB 32
#define KTOT 576      // CIN*9
#define ROWB 14592    // one input row in LDS: 114*64*2 bytes

static __device__ __forceinline__ u16 f2bf(float f) {
    u32 x = __float_as_uint(f);
    u32 r = (x + 0x7fffu + ((x >> 16) & 1u)) >> 16;
    return (u16)r;
}

#define MFMA16(a, b, c) __builtin_amdgcn_mfma_f32_16x16x32_bf16((a), (b), (c), 0, 0, 0)

static __device__ __forceinline__ void gload16(const void* g, void* l) {
    __builtin_amdgcn_global_load_lds(
        (const __attribute__((address_space(1))) unsigned int*)g,
        (__attribute__((address_space(3))) unsigned int*)l, 16, 0, 0);
}

// ---------------- fast path ----------------

// Merged pre-pass. Blocks [0,3648): x NCHW f32 -> xb bf16, swizzle baked:
//   xb[(b*114+h)*7296 + w*64 + (c8 ^ ((2h+w)&7))*8 + e] = x[b][8*c8+e][h][w]
// Blocks [3648,3936): weights -> bf16, K reordered to (kh,kw,ci).
__global__ __launch_bounds__(256) void prep(const float* __restrict__ x,
                                            const float* __restrict__ w,
                                            u16* __restrict__ xb,
                                            u16* __restrict__ wbf) {
    const int tid = threadIdx.x;
    const int blk = blockIdx.x;
    if (blk >= NB * XH) {
        int i = (blk - NB * XH) * 256 + tid;   // 73728 total, exact
        int o = i / KTOT;
        int rem = i - o * KTOT;
        int khkw = rem >> 6;
        int ci = rem & 63;
        wbf[i] = f2bf(w[(o * CINC + ci) * 9 + khkw]);
        return;
    }
    __shared__ u16 tile[XW * 70];   // [w][ci], u16 stride 70 (dword 35, coprime 32)
    const int b = blk / XH;
    const int h = blk - b * XH;

    #pragma unroll
    for (int it = 0; it < 15; ++it) {
        int idx = it * 256 + tid;
        if (idx < 32 * XW) {
            int cp = idx / XW;                  // 0..31
            int w_ = idx - cp * XW;
            const float* s0 = x + ((size_t)(b * CINC + 2 * cp) * XH + h) * XW + w_;
            float a = s0[0];
            float c = s0[XH * XW];
            u32 pk = (u32)f2bf(a) | ((u32)f2bf(c) << 16);
            *(u32*)&tile[w_ * 70 + 2 * cp] = pk;
        }
    }
    __syncthreads();

    u16* dstrow = xb + (size_t)(b * XH + h) * (XW * CINC);
    #pragma unroll
    for (int p2 = 0; p2 < 4; ++p2) {
        int task = p2 * 256 + tid;
        if (task < XW * 8) {
            int w_ = task >> 3;
            int c8 = task & 7;
            const u32* s = (const u32*)&tile[w_ * 70 + c8 * 8];
            u32x4 v = {s[0], s[1], s[2], s[3]};
            int slot = c8 ^ ((2 * h + w_) & 7);
            *(u32x4*)(dstrow + w_ * CINC + slot * 8) = v;
        }
    }
}

// Ring conv, 512 thr = 8 waves (4 cout-groups x 2 pixel-halves), 2 blocks/CU
// -> 16 waves/CU (VGPR must stay <=128). Each block: 7 single-row tiles of one
// batch; LDS = 4 row slots (slot = row & 3), one new row staged per tile via
// global_load_lds from swizzle-baked xb. Op-swapped MFMA; counted-vmcnt barrier.
__global__ __launch_bounds__(512, 4) void conv_ring8(const u16* __restrict__ xb,
                                                     const u16* __restrict__ wbf,
                                                     const float* __restrict__ bias,
                                                     float* __restrict__ out) {
    __shared__ u16 lds[4 * XW * CINC];   // 58368 B
    char* ldsc = (char*)lds;

    const int tid  = threadIdx.x;
    const int lane = tid & 63;
    const int wv   = tid >> 6;        // 0..7
    const int cg   = wv & 3;          // cout group [cg*32, cg*32+32)
    const int ns   = wv >> 2;         // pixel half: 0 -> nf0..3 @px0, 1 -> nf0..2 @px64
    const int nfn  = 4 - ns;
    const int l16  = lane & 15;
    const int lhi  = lane >> 4;

    int bidx = blockIdx.x;
    { int xcd = bidx & 7; bidx = xcd * 64 + (bidx >> 3); }   // 512 = 8*64 bijective
    const int bb = bidx >> 4;          // batch 0..31
    const int h0 = (bidx & 15) * 7;    // first output row

    // ---- weights + bias (compiler may L2-cache; VGPR budget 128) ----
    const u16* wrow0 = wbf + (cg * 32 + l16) * KTOT + lhi * 8;
    const u16* wrow1 = wrow0 + 16 * KTOT;
    const float bv0 = bias[cg * 32 + l16];
    const float bv1 = bias[cg * 32 + 16 + l16];

    // STAGE one input row into ring slot (row & 3): 15 chunks of 1024B
    // (chunk 14 = 256B); 8 waves take chunks it*8+wv, it=0..1 (c=15 skipped).
    auto STAGE = [&](int hin) {
        const char* src = (const char*)(xb + (size_t)(bb * XH + hin) * (XW * CINC));
        char* dst = ldsc + (hin & 3) * ROWB;
        #pragma unroll
        for (int it = 0; it < 2; ++it) {
            const int c = it * 8 + wv;
            const int off = c * 1024;
            if (c < 14) {
                gload16(src + off + lane * 16, dst + off);
            } else if (c == 14) {
                if (lane < 16) gload16(src + off + lane * 16, dst + off);
            }
        }
    };

    STAGE(h0); STAGE(h0 + 1); STAGE(h0 + 2);
    __builtin_amdgcn_sched_barrier(0);
    asm volatile("s_waitcnt vmcnt(0) lgkmcnt(0)" ::: "memory");
    __builtin_amdgcn_sched_barrier(0);
    __builtin_amdgcn_s_barrier();

    const f32x4 zero = {0.f, 0.f, 0.f, 0.f};

    #pragma unroll 1
    for (int i = 0; i < 7; ++i) {
        const int hrow = h0 + i;
        if (i < 6) STAGE(hrow + 3);   // slot (hrow+3)&3 disjoint from read slots

        f32x4 acc[2][4];
        #pragma unroll
        for (int mf = 0; mf < 2; ++mf)
            #pragma unroll
            for (int nf = 0; nf < 4; ++nf) acc[mf][nf] = zero;

        #pragma unroll
        for (int kh = 0; kh < 3; ++kh) {
            const int hin = hrow + kh;
            const int sb  = (hin & 3) * ROWB;
            #pragma unroll
            for (int kw = 0; kw < 3; ++kw) {
                const int tt = kh * 3 + kw;
                // pixel = kw + ns*64 + l16 + 16*nf ; 64&7==0 -> hash nf/ns-stable
                const int hash = (2 * hin + kw + l16) & 7;
                const int ba0 = sb + ((kw + ns * 64 + l16) << 7) + ((lhi ^ hash) << 4);
                short8 a0 = *(const short8*)(wrow0 + 2 * tt * 32);
                short8 a1 = *(const short8*)(wrow1 + 2 * tt * 32);
                short8 a0b = *(const short8*)(wrow0 + (2 * tt + 1) * 32);
                short8 a1b = *(const short8*)(wrow1 + (2 * tt + 1) * 32);
                #pragma unroll
                for (int nf = 0; nf < 4; ++nf) {
                    if (nf >= nfn) break;
                    short8 bf = *(const short8*)(ldsc + ba0 + nf * 2048);
                    acc[0][nf] = MFMA16(bf, a0, acc[0][nf]);
                    acc[1][nf] = MFMA16(bf, a1, acc[1][nf]);
                }
                #pragma unroll
                for (int nf = 0; nf < 4; ++nf) {
                    if (nf >= nfn) break;
                    short8 bf = *(const short8*)(ldsc + (ba0 ^ 0x40) + nf * 2048);
                    acc[0][nf] = MFMA16(bf, a0b, acc[0][nf]);
                    acc[1][nf] = MFMA16(bf, a1b, acc[1][nf]);
                }
            }
        }

        // epilogue: D row = pixel (lhi*4+j), col = cout (l16); <=8 dwordx4 stores
        #pragma unroll
        for (int mf = 0; mf < 2; ++mf) {
            const int o = cg * 32 + mf * 16 + l16;
            const float bv = mf ? bv1 : bv0;
            float* po = out + ((size_t)bb * COUT + o) * (OH * OW) + hrow * OW + ns * 64;
            #pragma unroll
            for (int nf = 0; nf < 4; ++nf) {
                if (nf >= nfn) break;
                f32x4 v = acc[mf][nf];
                v[0] += bv; v[1] += bv; v[2] += bv; v[3] += bv;
                *(f32x4*)(po + nf * 16 + lhi * 4) = v;
            }
        }

        // counted barrier. Per-wave in-loop vmem: ns0 = 8 stores + 2 stage,
        // ns1 = 6 stores + 2 stage. vmcnt(6): ns0 retires 18-6=12 >= 8old+2stage;
        // ns1 retires 14-6=8 >= 6old+2stage. Stage retired for BOTH; newest
        // stores keep floating.
        __builtin_amdgcn_sched_barrier(0);
        asm volatile("s_waitcnt vmcnt(6) lgkmcnt(0)" ::: "memory");
        __builtin_amdgcn_sched_barrier(0);
        __builtin_amdgcn_s_barrier();
    }
}

// ---------------- fallback (R0 kernel, needs only 147456 B ws) ----------------

#define BK 32
#define NSTEP 18
#define LDB 40

__global__ __launch_bounds__(256) void wcvt_ident(const float* __restrict__ w,
                                                  u16* __restrict__ wbf) {
    int i = blockIdx.x * 256 + threadIdx.x;
    if (i < COUT * KTOT) wbf[i] = f2bf(w[i]);
}

__global__ __launch_bounds__(256) void conv_fb(const float* __restrict__ x,
                                               const u16* __restrict__ wbf,
                                               const float* __restrict__ bias,
                                               float* __restrict__ out) {
    __shared__ u16 ldsB[OW * LDB];
    const int tid = threadIdx.x;
    int bid = blockIdx.x;
    { int xcd = bid & 7; bid = xcd * 448 + (bid >> 3); }
    const int b = bid / OH;
    const int h = bid - b * OH;
    const float* xbp = x + (size_t)b * (CINC * XH * XW);
    float* outb = out + (size_t)b * (COUT * OH * OW) + h * OW;
    const int lane = tid & 63, wv = tid >> 6, l16 = lane & 15, lhi = lane >> 4;
    const int m0 = wv * 32;
    const int sk = tid >> 3, sn0 = (tid & 7) * 14;
    f32x4 acc[2][7];
    const f32x4 zero = {0.f, 0.f, 0.f, 0.f};
    #pragma unroll
    for (int i = 0; i < 2; ++i)
        #pragma unroll
        for (int j = 0; j < 7; ++j) acc[i][j] = zero;
    for (int t = 0; t < NSTEP; ++t) {
        const int kg = t * BK + sk;
        const int ci = kg / 9;
        const int r9 = kg - ci * 9;
        const int kh = r9 / 3, kw = r9 - (r9 / 3) * 3;
        const float* src = xbp + ((size_t)ci * XH + (h + kh)) * XW + kw + sn0;
        __syncthreads();
        #pragma unroll
        for (int i = 0; i < 14; ++i) ldsB[(sn0 + i) * LDB + sk] = f2bf(src[i]);
        __syncthreads();
        short8 afrag[2];
        #pragma unroll
        for (int mf = 0; mf < 2; ++mf)
            afrag[mf] = *(const short8*)(wbf + (m0 + mf * 16 + l16) * KTOT + t * BK + lhi * 8);
        #pragma unroll
        for (int nf = 0; nf < 7; ++nf) {
            short8 bfrag = *(const short8*)&ldsB[(nf * 16 + l16) * LDB + lhi * 8];
            acc[0][nf] = MFMA16(afrag[0], bfrag, acc[0][nf]);
            acc[1][nf] = MFMA16(afrag[1], bfrag, acc[1][nf]);
        }
    }
    #pragma unroll
    for (int mf = 0; mf < 2; ++mf)
        #pragma unroll
        for (int j = 0; j < 4; ++j) {
            const int o = m0 + mf * 16 + lhi * 4 + j;
            const float bv = bias[o];
            #pragma unroll
            for (int nf = 0; nf < 7; ++nf)
                outb[(size_t)o * (OH * OW) + nf * 16 + l16] = acc[mf][nf][j] + bv;
        }
}

extern "C" void kernel_launch(void* const* d_in, const int* in_sizes, int n_in,
                              void* d_out, int out_size, void* d_ws, size_t ws_size,
                              hipStream_t stream) {
    const float* x    = (const float*)d_in[0];
    const float* w    = (const float*)d_in[3];
    const float* bias = (const float*)d_in[4];
    float* out = (float*)d_out;

    const size_t WBYTES = (size_t)COUT * KTOT * 2;                 // 147456
    const size_t XBYTES = (size_t)NB * XH * XW * CINC * 2;         // 53231616
    if (ws_size >= WBYTES + XBYTES) {
        u16* wbf = (u16*)d_ws;
        u16* xb  = (u16*)((char*)d_ws + WBYTES);
        prep<<<NB * XH + (COUT * KTOT) / 256, 256, 0, stream>>>(x, w, xb, wbf);
        conv_ring8<<<512, 512, 0, stream>>>(xb, wbf, bias, out);
    } else {
        u16* wbf = (u16*)d_ws;
        wcvt_ident<<<(COUT * KTOT + 255) / 256, 256, 0, stream>>>(w, wbf);
        conv_fb<<<NB * OH, 256, 0, stream>>>(x, wbf, bias, out);
    }
}

// Round 15
// 109.699 us; speedup vs baseline: 2.9703x; 2.9703x over previous
//
#include <hip/hip_runtime.h>

typedef __attribute__((ext_vector_type(8))) short short8;
typedef __attribute__((ext_vector_type(4))) float f32x4;
typedef __attribute__((ext_vector_type(4))) unsigned int u32x4;
typedef unsigned short u16;
typedef unsigned int u32;

#define XH 114
#define XW 114
#define CINC 64
#define COUT 128
#define OH 112
#define OW 112
#define NB 32
#define KTOT 576      // CIN*9
#define ROWB 14592    // one input row in LDS: 114*64*2 bytes

static __device__ __forceinline__ u16 f2bf(float f) {
    u32 x = __float_as_uint(f);
    u32 r = (x + 0x7fffu + ((x >> 16) & 1u)) >> 16;
    return (u16)r;
}

#define MFMA16(a, b, c) __builtin_amdgcn_mfma_f32_16x16x32_bf16((a), (b), (c), 0, 0, 0)

static __device__ __forceinline__ void gload16(const void* g, void* l) {
    __builtin_amdgcn_global_load_lds(
        (const __attribute__((address_space(1))) unsigned int*)g,
        (__attribute__((address_space(3))) unsigned int*)l, 16, 0, 0);
}

// ---------------- fast path ----------------

// Merged pre-pass. Blocks [0,3648): x NCHW f32 -> xb bf16, swizzle baked:
//   xb[(b*114+h)*7296 + w*64 + (c8 ^ ((2h+w)&7))*8 + e] = x[b][8*c8+e][h][w]
// Blocks [3648,3936): weights -> bf16, K reordered to (kh,kw,ci).
__global__ __launch_bounds__(256) void prep(const float* __restrict__ x,
                                            const float* __restrict__ w,
                                            u16* __restrict__ xb,
                                            u16* __restrict__ wbf) {
    const int tid = threadIdx.x;
    const int blk = blockIdx.x;
    if (blk >= NB * XH) {
        int i = (blk - NB * XH) * 256 + tid;   // 73728 total, exact
        int o = i / KTOT;
        int rem = i - o * KTOT;
        int khkw = rem >> 6;
        int ci = rem & 63;
        wbf[i] = f2bf(w[(o * CINC + ci) * 9 + khkw]);
        return;
    }
    __shared__ u16 tile[XW * 70];   // [w][ci], u16 stride 70 (dword 35, coprime 32)
    const int b = blk / XH;
    const int h = blk - b * XH;

    #pragma unroll
    for (int it = 0; it < 15; ++it) {
        int idx = it * 256 + tid;
        if (idx < 32 * XW) {
            int cp = idx / XW;                  // 0..31
            int w_ = idx - cp * XW;
            const float* s0 = x + ((size_t)(b * CINC + 2 * cp) * XH + h) * XW + w_;
            float a = s0[0];
            float c = s0[XH * XW];
            u32 pk = (u32)f2bf(a) | ((u32)f2bf(c) << 16);
            *(u32*)&tile[w_ * 70 + 2 * cp] = pk;
        }
    }
    __syncthreads();

    u16* dstrow = xb + (size_t)(b * XH + h) * (XW * CINC);
    #pragma unroll
    for (int p2 = 0; p2 < 4; ++p2) {
        int task = p2 * 256 + tid;
        if (task < XW * 8) {
            int w_ = task >> 3;
            int c8 = task & 7;
            const u32* s = (const u32*)&tile[w_ * 70 + c8 * 8];
            u32x4 v = {s[0], s[1], s[2], s[3]};
            int slot = c8 ^ ((2 * h + w_) & 7);
            *(u32x4*)(dstrow + w_ * CINC + slot * 8) = v;
        }
    }
}

// Ring-buffer conv (R9 champion + T5 setprio): 512 blocks x 256 thr (4 waves =
// 4 cout-groups), 2 independent blocks/CU. 7 single-row tiles per block; LDS =
// 4 row slots (slot = row & 3); one new row staged per tile via global_load_lds
// from swizzle-baked xb. A (weights) in regs; op-swapped MFMA; counted-vmcnt
// barrier. setprio(1) wraps each kw MFMA cluster (2 staggered blocks/CU give
// the role diversity T5 needs).
__global__ __launch_bounds__(256, 2) void conv_ring(const u16* __restrict__ xb,
                                                    const u16* __restrict__ wbf,
                                                    const float* __restrict__ bias,
                                                    float* __restrict__ out) {
    __shared__ u16 lds[4 * XW * CINC];   // 58368 B
    char* ldsc = (char*)lds;

    const int tid  = threadIdx.x;
    const int lane = tid & 63;
    const int wv   = tid >> 6;        // 0..3 = cout group
    const int l16  = lane & 15;
    const int lhi  = lane >> 4;

    int bidx = blockIdx.x;
    { int xcd = bidx & 7; bidx = xcd * 64 + (bidx >> 3); }   // 512 = 8*64 bijective
    const int bb = bidx >> 4;          // batch 0..31
    const int h0 = (bidx & 15) * 7;    // first output row

    // ---- prologue: weights + bias in registers ----
    const u16* wrow0 = wbf + (wv * 32 + l16) * KTOT + lhi * 8;
    const u16* wrow1 = wrow0 + 16 * KTOT;
    short8 areg0[18], areg1[18];
    #pragma unroll
    for (int t = 0; t < 18; ++t) {
        areg0[t] = *(const short8*)(wrow0 + t * 32);
        areg1[t] = *(const short8*)(wrow1 + t * 32);
    }
    const float bv0 = bias[wv * 32 + l16];
    const float bv1 = bias[wv * 32 + 16 + l16];

    // STAGE one input row into its ring slot: 15 chunks of 1024B (last = 256B)
    // wave wv takes chunks it*4+wv; LDS dest wave-uniform, global src +lane*16.
    auto STAGE = [&](int hin) {
        const char* src = (const char*)(xb + (size_t)(bb * XH + hin) * (XW * CINC));
        char* dst = ldsc + (hin & 3) * ROWB;
        #pragma unroll
        for (int it = 0; it < 4; ++it) {
            const int c = it * 4 + wv;
            const int off = c * 1024;
            if (c < 14) {
                gload16(src + off + lane * 16, dst + off);
            } else if (c == 14) {
                if (lane < 16) gload16(src + off + lane * 16, dst + off);
            }
        }
    };

    STAGE(h0); STAGE(h0 + 1); STAGE(h0 + 2);
    __builtin_amdgcn_sched_barrier(0);
    asm volatile("s_waitcnt vmcnt(0) lgkmcnt(0)" ::: "memory");
    __builtin_amdgcn_sched_barrier(0);
    __builtin_amdgcn_s_barrier();

    const f32x4 zero = {0.f, 0.f, 0.f, 0.f};

    #pragma unroll 1
    for (int i = 0; i < 7; ++i) {
        const int hrow = h0 + i;
        // stage next-needed row (slot (hrow+3)&3 is disjoint from read slots)
        if (i < 6) STAGE(hrow + 3);

        f32x4 acc[2][7];
        #pragma unroll
        for (int mf = 0; mf < 2; ++mf)
            #pragma unroll
            for (int nf = 0; nf < 7; ++nf) acc[mf][nf] = zero;

        #pragma unroll
        for (int kh = 0; kh < 3; ++kh) {
            const int hin = hrow + kh;                       // input row
            const int sb  = (hin & 3) * ROWB;
            #pragma unroll
            for (int kw = 0; kw < 3; ++kw) {
                const int tt = kh * 3 + kw;
                const int hash = (2 * hin + kw + l16) & 7;   // nf-invariant
                const int ba0 = sb + ((kw + l16) << 7) + ((lhi ^ hash) << 4);

                __builtin_amdgcn_s_setprio(1);
                #pragma unroll
                for (int nf = 0; nf < 7; ++nf) {
                    short8 bf = *(const short8*)(ldsc + ba0 + nf * 2048);
                    acc[0][nf] = MFMA16(bf, areg0[2 * tt], acc[0][nf]);
                    acc[1][nf] = MFMA16(bf, areg1[2 * tt], acc[1][nf]);
                }
                #pragma unroll
                for (int nf = 0; nf < 7; ++nf) {
                    short8 bf = *(const short8*)(ldsc + (ba0 ^ 0x40) + nf * 2048);
                    acc[0][nf] = MFMA16(bf, areg0[2 * tt + 1], acc[0][nf]);
                    acc[1][nf] = MFMA16(bf, areg1[2 * tt + 1], acc[1][nf]);
                }
                __builtin_amdgcn_s_setprio(0);
            }
        }

        // epilogue: D row = pixel (lhi*4+j), col = cout (l16); 14 dwordx4 stores
        #pragma unroll
        for (int mf = 0; mf < 2; ++mf) {
            const int o = wv * 32 + mf * 16 + l16;
            const float bv = mf ? bv1 : bv0;
            float* po = out + ((size_t)bb * COUT + o) * (OH * OW) + hrow * OW;
            #pragma unroll
            for (int nf = 0; nf < 7; ++nf) {
                f32x4 v = acc[mf][nf];
                v[0] += bv; v[1] += bv; v[2] += bv; v[3] += bv;
                *(f32x4*)(po + nf * 16 + lhi * 4) = v;
            }
        }

        // counted barrier: outstanding = old stores(<=14) + stage(<=4) + stores(14);
        // vmcnt(14) retires old stores + this tile's staging; new stores float.
        __builtin_amdgcn_sched_barrier(0);
        asm volatile("s_waitcnt vmcnt(14) lgkmcnt(0)" ::: "memory");
        __builtin_amdgcn_sched_barrier(0);
        __builtin_amdgcn_s_barrier();
    }
}

// ---------------- fallback (R0 kernel, needs only 147456 B ws) ----------------

#define BK 32
#define NSTEP 18
#define LDB 40

__global__ __launch_bounds__(256) void wcvt_ident(const float* __restrict__ w,
                                                  u16* __restrict__ wbf) {
    int i = blockIdx.x * 256 + threadIdx.x;
    if (i < COUT * KTOT) wbf[i] = f2bf(w[i]);
}

__global__ __launch_bounds__(256) void conv_fb(const float* __restrict__ x,
                                               const u16* __restrict__ wbf,
                                               const float* __restrict__ bias,
                                               float* __restrict__ out) {
    __shared__ u16 ldsB[OW * LDB];
    const int tid = threadIdx.x;
    int bid = blockIdx.x;
    { int xcd = bid & 7; bid = xcd * 448 + (bid >> 3); }
    const int b = bid / OH;
    const int h = bid - b * OH;
    const float* xbp = x + (size_t)b * (CINC * XH * XW);
    float* outb = out + (size_t)b * (COUT * OH * OW) + h * OW;
    const int lane = tid & 63, wv = tid >> 6, l16 = lane & 15, lhi = lane >> 4;
    const int m0 = wv * 32;
    const int sk = tid >> 3, sn0 = (tid & 7) * 14;
    f32x4 acc[2][7];
    const f32x4 zero = {0.f, 0.f, 0.f, 0.f};
    #pragma unroll
    for (int i = 0; i < 2; ++i)
        #pragma unroll
        for (int j = 0; j < 7; ++j) acc[i][j] = zero;
    for (int t = 0; t < NSTEP; ++t) {
        const int kg = t * BK + sk;
        const int ci = kg / 9;
        const int r9 = kg - ci * 9;
        const int kh = r9 / 3, kw = r9 - (r9 / 3) * 3;
        const float* src = xbp + ((size_t)ci * XH + (h + kh)) * XW + kw + sn0;
        __syncthreads();
        #pragma unroll
        for (int i = 0; i < 14; ++i) ldsB[(sn0 + i) * LDB + sk] = f2bf(src[i]);
        __syncthreads();
        short8 afrag[2];
        #pragma unroll
        for (int mf = 0; mf < 2; ++mf)
            afrag[mf] = *(const short8*)(wbf + (m0 + mf * 16 + l16) * KTOT + t * BK + lhi * 8);
        #pragma unroll
        for (int nf = 0; nf < 7; ++nf) {
            short8 bfrag = *(const short8*)&ldsB[(nf * 16 + l16) * LDB + lhi * 8];
            acc[0][nf] = MFMA16(afrag[0], bfrag, acc[0][nf]);
            acc[1][nf] = MFMA16(afrag[1], bfrag, acc[1][nf]);
        }
    }
    #pragma unroll
    for (int mf = 0; mf < 2; ++mf)
        #pragma unroll
        for (int j = 0; j < 4; ++j) {
            const int o = m0 + mf * 16 + lhi * 4 + j;
            const float bv = bias[o];
            #pragma unroll
            for (int nf = 0; nf < 7; ++nf)
                outb[(size_t)o * (OH * OW) + nf * 16 + l16] = acc[mf][nf][j] + bv;
        }
}

extern "C" void kernel_launch(void* const* d_in, const int* in_sizes, int n_in,
                              void* d_out, int out_size, void* d_ws, size_t ws_size,
                              hipStream_t stream) {
    const float* x    = (const float*)d_in[0];
    const float* w    = (const float*)d_in[3];
    const float* bias = (const float*)d_in[4];
    float* out = (float*)d_out;

    const size_t WBYTES = (size_t)COUT * KTOT * 2;                 // 147456
    const size_t XBYTES = (size_t)NB * XH * XW * CINC * 2;         // 53231616
    if (ws_size >= WBYTES + XBYTES) {
        u16* wbf = (u16*)d_ws;
        u16* xb  = (u16*)((char*)d_ws + WBYTES);
        prep<<<NB * XH + (COUT * KTOT) / 256, 256, 0, stream>>>(x, w, xb, wbf);
        conv_ring<<<512, 256, 0, stream>>>(xb, wbf, bias, out);
    } else {
        u16* wbf = (u16*)d_ws;
        wcvt_ident<<<(COUT * KTOT + 255) / 256, 256, 0, stream>>>(w, wbf);
        conv_fb<<<NB * OH, 256, 0, stream>>>(x, wbf, bias, out);
    }
}